// Round 4
// baseline (412.929 us; speedup 1.0000x reference)
//
#include <hip/hip_runtime.h>
#include <cmath>

#define BB 4
#define TT 2048
#define CC 1024
#define HH 16
#define DD 64
#define MM (BB*TT)   // 8192

typedef _Float16 f16x8 __attribute__((ext_vector_type(8)));
typedef float f32x4 __attribute__((ext_vector_type(4)));
typedef unsigned short ushort_t;

__device__ __forceinline__ unsigned short f2h(float f) {
    _Float16 h = (_Float16)f;
    return __builtin_bit_cast(unsigned short, h);
}

// async global->LDS, 16 bytes per lane (lane i -> base + i*16).
__device__ __forceinline__ void gld16(const void* gsrc, void* ldst) {
    void* g = const_cast<void*>(gsrc);
    __builtin_amdgcn_global_load_lds(
        (__attribute__((address_space(1))) void*)g,
        (__attribute__((address_space(3))) void*)ldst,
        16, 0, 0);
}

// ---------------------------------------------------------------------------
// prep: fp32 -> f16 (packed x4)
// ---------------------------------------------------------------------------
__global__ __launch_bounds__(256)
void cvt4_kernel(const float* __restrict__ in, ushort_t* __restrict__ out, long n4) {
    long i = (long)blockIdx.x * blockDim.x + threadIdx.x;
    if (i >= n4) return;
    float4 v = ((const float4*)in)[i];
    ushort4 o;
    o.x = f2h(v.x); o.y = f2h(v.y); o.z = f2h(v.z); o.w = f2h(v.w);
    ((ushort4*)out)[i] = o;
}

// ---------------------------------------------------------------------------
// prep: transpose + convert: in[K][N] fp32 -> out[N][K] f16. 32x32 tiles.
// ---------------------------------------------------------------------------
__global__ __launch_bounds__(256)
void trcvt_kernel(const float* __restrict__ in, ushort_t* __restrict__ out,
                  int K, int N) {
    __shared__ float T[32][33];
    const int tx = threadIdx.x & 31;
    const int ty = threadIdx.x >> 5;
    const int n0 = blockIdx.x * 32;
    const int k0 = blockIdx.y * 32;
    #pragma unroll
    for (int i = 0; i < 4; ++i)
        T[ty + i * 8][tx] = in[(size_t)(k0 + ty + i * 8) * N + n0 + tx];
    __syncthreads();
    #pragma unroll
    for (int i = 0; i < 4; ++i)
        out[(size_t)(n0 + ty + i * 8) * K + k0 + tx] = f2h(T[tx][ty + i * 8]);
}

// ---------------------------------------------------------------------------
// f16 MFMA GEMM (m97 structure): C[M,N] = A[M,1024] @ B[1024,N] + bias
// QKV epilogue: q,k f16 [B,H,T,D]; q pre-scaled by 8*log2(e) (exp2 softmax
// domain); v f16 TRANSPOSED [B,H,D,T].
// ---------------------------------------------------------------------------
template<int N, bool QKV>
__global__ __launch_bounds__(256)
void hgemm_kernel(const ushort_t* __restrict__ A, const ushort_t* __restrict__ Bt,
                  const float* __restrict__ bias, float* __restrict__ out,
                  ushort_t* __restrict__ qh, ushort_t* __restrict__ kh,
                  ushort_t* __restrict__ vh)
{
    const int K = 1024;
    __shared__ ushort_t As[128 * 32];
    __shared__ ushort_t Bs[128 * 32];

    const int tid  = threadIdx.x;
    const int lane = tid & 63;
    const int wave = tid >> 6;
    const int wm   = (wave & 1) * 64;
    const int wn   = (wave >> 1) * 64;
    const int m0   = blockIdx.y * 128;
    const int n0   = blockIdx.x * 128;
    const int lrow = lane & 15;
    const int quad = lane >> 4;

    const int u0 = wave * 64 + lane;
    const int u1 = u0 + 256;
    const size_t gA0 = (size_t)(m0 + (u0 >> 2)) * K + (u0 & 3) * 8;
    const size_t gA1 = (size_t)(m0 + (u1 >> 2)) * K + (u1 & 3) * 8;
    const size_t gB0 = (size_t)(n0 + (u0 >> 2)) * K + (u0 & 3) * 8;
    const size_t gB1 = (size_t)(n0 + (u1 >> 2)) * K + (u1 & 3) * 8;
    ushort_t* ldsA0 = &As[(wave * 64) * 8];
    ushort_t* ldsA1 = &As[(256 + wave * 64) * 8];
    ushort_t* ldsB0 = &Bs[(wave * 64) * 8];
    ushort_t* ldsB1 = &Bs[(256 + wave * 64) * 8];

    f32x4 acc[4][4];
    const f32x4 z = {0.f, 0.f, 0.f, 0.f};
    #pragma unroll
    for (int mt = 0; mt < 4; ++mt)
        #pragma unroll
        for (int nt = 0; nt < 4; ++nt)
            acc[mt][nt] = z;

    for (int kk = 0; kk < K; kk += 32) {
        gld16(&A[gA0 + kk],  ldsA0);
        gld16(&A[gA1 + kk],  ldsA1);
        gld16(&Bt[gB0 + kk], ldsB0);
        gld16(&Bt[gB1 + kk], ldsB1);
        __syncthreads();

        f16x8 af[4], bf[4];
        #pragma unroll
        for (int mt = 0; mt < 4; ++mt)
            af[mt] = *(const f16x8*)&As[(wm + mt * 16 + lrow) * 32 + quad * 8];
        #pragma unroll
        for (int nt = 0; nt < 4; ++nt)
            bf[nt] = *(const f16x8*)&Bs[(wn + nt * 16 + lrow) * 32 + quad * 8];
        #pragma unroll
        for (int mt = 0; mt < 4; ++mt)
            #pragma unroll
            for (int nt = 0; nt < 4; ++nt)
                acc[mt][nt] = __builtin_amdgcn_mfma_f32_16x16x32_f16(
                    af[mt], bf[nt], acc[mt][nt], 0, 0, 0);
        __syncthreads();
    }

    #pragma unroll
    for (int mt = 0; mt < 4; ++mt) {
        const int rbase = m0 + wm + mt * 16 + quad * 4;
        #pragma unroll
        for (int nt = 0; nt < 4; ++nt) {
            const int col = n0 + wn + nt * 16 + lrow;
            const float bv = bias[col];
            if (QKV) {
                const int which = col >> 10;
                const int c = col & 1023;
                const int h = c >> 6, d = c & 63;
                const int b = rbase >> 11, t0 = rbase & 2047;
                if (which == 2) {
                    ushort4 pk;
                    pk.x = f2h(acc[mt][nt][0] + bv);
                    pk.y = f2h(acc[mt][nt][1] + bv);
                    pk.z = f2h(acc[mt][nt][2] + bv);
                    pk.w = f2h(acc[mt][nt][3] + bv);
                    *(ushort4*)&vh[(((size_t)b * HH + h) * DD + d) * TT + t0] = pk;
                } else {
                    ushort_t* dst = which ? kh : qh;
                    // q carries score-scale 8 and log2(e) for exp2-domain softmax
                    const float sc = which ? 1.0f : 8.0f * 1.44269504088896f;
                    #pragma unroll
                    for (int r = 0; r < 4; ++r)
                        dst[(((size_t)b * HH + h) * TT + t0 + r) * DD + d] =
                            f2h((acc[mt][nt][r] + bv) * sc);
                }
            } else {
                #pragma unroll
                for (int r = 0; r < 4; ++r)
                    out[(size_t)(rbase + r) * N + col] = acc[mt][nt][r] + bv;
            }
        }
    }
}

// ---------------------------------------------------------------------------
// Barrier-free MFMA flash attention. One wave (64 thr) per block; each wave
// owns 32 q rows (2 x 16-row MFMA strips) and loops over 64-key tiles.
// K/V B-fragments are loaded DIRECTLY from global (uint4 per lane matches the
// MFMA B-frag layout) -- no LDS staging, no __syncthreads. LDS holds only the
// per-wave P strip (32x68 halves) for the C-layout -> A-layout transpose
// (same-wave RAW, in-order). Softmax runs in exp2 domain (scale pre-folded).
// qh,kh: f16 [B*H][T][D]; vh: f16 [B*H][D][T]; yh: f16 [B*T][C].
// ---------------------------------------------------------------------------
__global__ __launch_bounds__(64, 3)
void attn_mfma_kernel(const ushort_t* __restrict__ qh, const ushort_t* __restrict__ kh,
                      const ushort_t* __restrict__ vh, ushort_t* __restrict__ yh)
{
    __shared__ ushort_t Ps[32 * 68];   // [q][key], padded row 68

    const int qi   = (int)gridDim.x - 1 - (int)blockIdx.x;  // big blocks first
    const int bh   = blockIdx.y;
    const int lane = threadIdx.x;
    const int lrow = lane & 15;
    const int quad = lane >> 4;
    const int q0   = qi * 32;

    const ushort_t* qbase = qh + (size_t)bh * TT * DD;
    const ushort_t* kbase = kh + (size_t)bh * TT * DD;
    const ushort_t* vbase = vh + (size_t)bh * DD * TT;

    // Q A-fragments: strip s rows q0+s*16+lrow, k-halves [0,32) and [32,64)
    f16x8 aq[2][2];
    #pragma unroll
    for (int s = 0; s < 2; ++s) {
        aq[s][0] = *(const f16x8*)&qbase[(size_t)(q0 + s * 16 + lrow) * DD + quad * 8];
        aq[s][1] = *(const f16x8*)&qbase[(size_t)(q0 + s * 16 + lrow) * DD + 32 + quad * 8];
    }

    f32x4 o[2][4];
    float mi[2][4], li[2][4];
    const f32x4 z = {0.f, 0.f, 0.f, 0.f};
    #pragma unroll
    for (int s = 0; s < 2; ++s)
        #pragma unroll
        for (int i = 0; i < 4; ++i) { o[s][i] = z; mi[s][i] = -1e30f; li[s][i] = 0.f; }

    const int ktmax = (q0 + 31) >> 6;
    for (int kt = 0; kt <= ktmax; ++kt) {
        // K B-frags: lane holds K[key=c*16+lrow][d=quad*8..+8] -- direct global
        f16x8 kf[4][2], vf[4][2];
        #pragma unroll
        for (int c = 0; c < 4; ++c) {
            const ushort_t* kp = &kbase[(size_t)(kt * 64 + c * 16 + lrow) * DD + quad * 8];
            kf[c][0] = *(const f16x8*)kp;
            kf[c][1] = *(const f16x8*)(kp + 32);
        }
        // V B-frags: lane holds V^T[d=dt*16+lrow][key=quad*8..+8] -- direct global
        #pragma unroll
        for (int dt = 0; dt < 4; ++dt) {
            const ushort_t* vp = &vbase[(size_t)(dt * 16 + lrow) * TT + kt * 64 + quad * 8];
            vf[dt][0] = *(const f16x8*)vp;
            vf[dt][1] = *(const f16x8*)(vp + 32);
        }

        const bool diag = (kt == ktmax);
        #pragma unroll
        for (int s = 0; s < 2; ++s) {
            // S strip = Q K^T
            f32x4 sv[4];
            #pragma unroll
            for (int c = 0; c < 4; ++c) {
                sv[c] = __builtin_amdgcn_mfma_f32_16x16x32_f16(aq[s][0], kf[c][0], z, 0, 0, 0);
                sv[c] = __builtin_amdgcn_mfma_f32_16x16x32_f16(aq[s][1], kf[c][1], sv[c], 0, 0, 0);
            }
            // online softmax, exp2 domain (C-layout: row=quad*4+r, col=c*16+lrow)
            #pragma unroll
            for (int r = 0; r < 4; ++r) {
                if (diag) {
                    const int qg = q0 + s * 16 + quad * 4 + r;
                    #pragma unroll
                    for (int c = 0; c < 4; ++c)
                        if (kt * 64 + c * 16 + lrow > qg) sv[c][r] = -3e38f;
                }
                float m = fmaxf(fmaxf(sv[0][r], sv[1][r]), fmaxf(sv[2][r], sv[3][r]));
                #pragma unroll
                for (int off = 1; off < 16; off <<= 1)
                    m = fmaxf(m, __shfl_xor(m, off, 64));
                const float mnew  = fmaxf(mi[s][r], m);
                const float alpha = exp2f(mi[s][r] - mnew);
                float rs = 0.f;
                #pragma unroll
                for (int c = 0; c < 4; ++c) {
                    const float p = exp2f(sv[c][r] - mnew);
                    rs += p;
                    Ps[(s * 16 + quad * 4 + r) * 68 + c * 16 + lrow] = f2h(p);
                }
                #pragma unroll
                for (int off = 1; off < 16; off <<= 1)
                    rs += __shfl_xor(rs, off, 64);
                li[s][r] = li[s][r] * alpha + rs;
                mi[s][r] = mnew;
                #pragma unroll
                for (int dt = 0; dt < 4; ++dt) o[s][dt][r] *= alpha;
            }
        }

        // O += P V (P strip back through LDS as A-frags; same-wave, no barrier)
        #pragma unroll
        for (int s = 0; s < 2; ++s) {
            f16x8 ap0 = *(const f16x8*)&Ps[(s * 16 + lrow) * 68 + quad * 8];
            f16x8 ap1 = *(const f16x8*)&Ps[(s * 16 + lrow) * 68 + 32 + quad * 8];
            #pragma unroll
            for (int dt = 0; dt < 4; ++dt) {
                o[s][dt] = __builtin_amdgcn_mfma_f32_16x16x32_f16(ap0, vf[dt][0], o[s][dt], 0, 0, 0);
                o[s][dt] = __builtin_amdgcn_mfma_f32_16x16x32_f16(ap1, vf[dt][1], o[s][dt], 0, 0, 0);
            }
        }
    }

    // normalize + write y f16 [B*T][C]
    const int b = bh >> 4, h = bh & 15;
    #pragma unroll
    for (int s = 0; s < 2; ++s)
        #pragma unroll
        for (int r = 0; r < 4; ++r) {
            const float inv = 1.0f / li[s][r];
            const int t = q0 + s * 16 + quad * 4 + r;
            #pragma unroll
            for (int dt = 0; dt < 4; ++dt)
                yh[((size_t)b * TT + t) * CC + h * 64 + dt * 16 + lrow] =
                    f2h(o[s][dt][r] * inv);
        }
}

// ---------------------------------------------------------------------------
// ws layout (halves): qh | kh | vh (8.39M each) | xh 8.39M (yh aliases xh)
//                     | wat 3.15M | wpt 1.05M     ~ 75 MB
// ---------------------------------------------------------------------------
extern "C" void kernel_launch(void* const* d_in, const int* in_sizes, int n_in,
                              void* d_out, int out_size, void* d_ws, size_t ws_size,
                              hipStream_t stream) {
    const float* x      = (const float*)d_in[0];
    const float* w_attn = (const float*)d_in[1];
    const float* b_attn = (const float*)d_in[2];
    const float* w_proj = (const float*)d_in[3];
    const float* b_proj = (const float*)d_in[4];
    float* out = (float*)d_out;

    const size_t per = (size_t)BB * HH * TT * DD;      // 8,388,608
    ushort_t* qh  = (ushort_t*)d_ws;
    ushort_t* kh  = qh + per;
    ushort_t* vh  = kh + per;
    ushort_t* xh  = vh + per;
    ushort_t* yh  = xh;                                 // alias: xh dead after GEMM1
    ushort_t* wat = xh + (size_t)MM * CC;
    ushort_t* wpt = wat + (size_t)3 * CC * CC;

    cvt4_kernel<<<(MM * CC / 4 + 255) / 256, 256, 0, stream>>>(x, xh, MM * CC / 4);
    trcvt_kernel<<<dim3(3 * CC / 32, CC / 32), 256, 0, stream>>>(w_attn, wat, CC, 3 * CC);
    trcvt_kernel<<<dim3(CC / 32, CC / 32), 256, 0, stream>>>(w_proj, wpt, CC, CC);

    hgemm_kernel<3 * CC, true><<<dim3(3 * CC / 128, MM / 128), 256, 0, stream>>>(
        xh, wat, b_attn, nullptr, qh, kh, vh);

    // one wave per block: 64 q-tiles of 32 rows (x, reversed: big first) x 64 heads (y)
    attn_mfma_kernel<<<dim3(TT / 32, BB * HH), 64, 0, stream>>>(qh, kh, vh, yh);

    hgemm_kernel<CC, false><<<dim3(CC / 128, MM / 128), 256, 0, stream>>>(
        yh, wpt, b_proj, out, nullptr, nullptr, nullptr);
}

// Round 6
// 400.452 us; speedup vs baseline: 1.0312x; 1.0312x over previous
//
#include <hip/hip_runtime.h>
#include <cmath>

#define BB 4
#define TT 2048
#define CC 1024
#define HH 16
#define DD 64
#define MM (BB*TT)   // 8192

typedef _Float16 f16x8 __attribute__((ext_vector_type(8)));
typedef float f32x4 __attribute__((ext_vector_type(4)));
typedef unsigned short ushort_t;

__device__ __forceinline__ unsigned short f2h(float f) {
    _Float16 h = (_Float16)f;
    return __builtin_bit_cast(unsigned short, h);
}

// async global->LDS, 16 bytes per lane (lane i -> base + i*16).
__device__ __forceinline__ void gld16(const void* gsrc, void* ldst) {
    void* g = const_cast<void*>(gsrc);
    __builtin_amdgcn_global_load_lds(
        (__attribute__((address_space(1))) void*)g,
        (__attribute__((address_space(3))) void*)ldst,
        16, 0, 0);
}

// ---------------------------------------------------------------------------
// prep: fp32 -> f16 (packed x4)
// ---------------------------------------------------------------------------
__global__ __launch_bounds__(256)
void cvt4_kernel(const float* __restrict__ in, ushort_t* __restrict__ out, long n4) {
    long i = (long)blockIdx.x * blockDim.x + threadIdx.x;
    if (i >= n4) return;
    float4 v = ((const float4*)in)[i];
    ushort4 o;
    o.x = f2h(v.x); o.y = f2h(v.y); o.z = f2h(v.z); o.w = f2h(v.w);
    ((ushort4*)out)[i] = o;
}

// ---------------------------------------------------------------------------
// prep: transpose + convert: in[K][N] fp32 -> out[N][K] f16. 32x32 tiles.
// ---------------------------------------------------------------------------
__global__ __launch_bounds__(256)
void trcvt_kernel(const float* __restrict__ in, ushort_t* __restrict__ out,
                  int K, int N) {
    __shared__ float T[32][33];
    const int tx = threadIdx.x & 31;
    const int ty = threadIdx.x >> 5;
    const int n0 = blockIdx.x * 32;
    const int k0 = blockIdx.y * 32;
    #pragma unroll
    for (int i = 0; i < 4; ++i)
        T[ty + i * 8][tx] = in[(size_t)(k0 + ty + i * 8) * N + n0 + tx];
    __syncthreads();
    #pragma unroll
    for (int i = 0; i < 4; ++i)
        out[(size_t)(n0 + ty + i * 8) * K + k0 + tx] = f2h(T[tx][ty + i * 8]);
}

// ---------------------------------------------------------------------------
// f16 MFMA GEMM (m97 structure): C[M,N] = A[M,1024] @ B[1024,N] + bias
// QKV epilogue: q,k f16 [B,H,T,D]; q pre-scaled by 8*log2(e) (exp2 softmax
// domain); v f16 TRANSPOSED [B,H,D,T].
// ---------------------------------------------------------------------------
template<int N, bool QKV>
__global__ __launch_bounds__(256)
void hgemm_kernel(const ushort_t* __restrict__ A, const ushort_t* __restrict__ Bt,
                  const float* __restrict__ bias, float* __restrict__ out,
                  ushort_t* __restrict__ qh, ushort_t* __restrict__ kh,
                  ushort_t* __restrict__ vh)
{
    const int K = 1024;
    __shared__ ushort_t As[128 * 32];
    __shared__ ushort_t Bs[128 * 32];

    const int tid  = threadIdx.x;
    const int lane = tid & 63;
    const int wave = tid >> 6;
    const int wm   = (wave & 1) * 64;
    const int wn   = (wave >> 1) * 64;
    const int m0   = blockIdx.y * 128;
    const int n0   = blockIdx.x * 128;
    const int lrow = lane & 15;
    const int quad = lane >> 4;

    const int u0 = wave * 64 + lane;
    const int u1 = u0 + 256;
    const size_t gA0 = (size_t)(m0 + (u0 >> 2)) * K + (u0 & 3) * 8;
    const size_t gA1 = (size_t)(m0 + (u1 >> 2)) * K + (u1 & 3) * 8;
    const size_t gB0 = (size_t)(n0 + (u0 >> 2)) * K + (u0 & 3) * 8;
    const size_t gB1 = (size_t)(n0 + (u1 >> 2)) * K + (u1 & 3) * 8;
    ushort_t* ldsA0 = &As[(wave * 64) * 8];
    ushort_t* ldsA1 = &As[(256 + wave * 64) * 8];
    ushort_t* ldsB0 = &Bs[(wave * 64) * 8];
    ushort_t* ldsB1 = &Bs[(256 + wave * 64) * 8];

    f32x4 acc[4][4];
    const f32x4 z = {0.f, 0.f, 0.f, 0.f};
    #pragma unroll
    for (int mt = 0; mt < 4; ++mt)
        #pragma unroll
        for (int nt = 0; nt < 4; ++nt)
            acc[mt][nt] = z;

    for (int kk = 0; kk < K; kk += 32) {
        gld16(&A[gA0 + kk],  ldsA0);
        gld16(&A[gA1 + kk],  ldsA1);
        gld16(&Bt[gB0 + kk], ldsB0);
        gld16(&Bt[gB1 + kk], ldsB1);
        __syncthreads();

        f16x8 af[4], bf[4];
        #pragma unroll
        for (int mt = 0; mt < 4; ++mt)
            af[mt] = *(const f16x8*)&As[(wm + mt * 16 + lrow) * 32 + quad * 8];
        #pragma unroll
        for (int nt = 0; nt < 4; ++nt)
            bf[nt] = *(const f16x8*)&Bs[(wn + nt * 16 + lrow) * 32 + quad * 8];
        #pragma unroll
        for (int mt = 0; mt < 4; ++mt)
            #pragma unroll
            for (int nt = 0; nt < 4; ++nt)
                acc[mt][nt] = __builtin_amdgcn_mfma_f32_16x16x32_f16(
                    af[mt], bf[nt], acc[mt][nt], 0, 0, 0);
        __syncthreads();
    }

    #pragma unroll
    for (int mt = 0; mt < 4; ++mt) {
        const int rbase = m0 + wm + mt * 16 + quad * 4;
        #pragma unroll
        for (int nt = 0; nt < 4; ++nt) {
            const int col = n0 + wn + nt * 16 + lrow;
            const float bv = bias[col];
            if (QKV) {
                const int which = col >> 10;
                const int c = col & 1023;
                const int h = c >> 6, d = c & 63;
                const int b = rbase >> 11, t0 = rbase & 2047;
                if (which == 2) {
                    ushort4 pk;
                    pk.x = f2h(acc[mt][nt][0] + bv);
                    pk.y = f2h(acc[mt][nt][1] + bv);
                    pk.z = f2h(acc[mt][nt][2] + bv);
                    pk.w = f2h(acc[mt][nt][3] + bv);
                    *(ushort4*)&vh[(((size_t)b * HH + h) * DD + d) * TT + t0] = pk;
                } else {
                    ushort_t* dst = which ? kh : qh;
                    // q carries score-scale 8 and log2(e) for exp2-domain softmax
                    const float sc = which ? 1.0f : 8.0f * 1.44269504088896f;
                    #pragma unroll
                    for (int r = 0; r < 4; ++r)
                        dst[(((size_t)b * HH + h) * TT + t0 + r) * DD + d] =
                            f2h((acc[mt][nt][r] + bv) * sc);
                }
            } else {
                #pragma unroll
                for (int r = 0; r < 4; ++r)
                    out[(size_t)(rbase + r) * N + col] = acc[mt][nt][r] + bv;
            }
        }
    }
}

// ---------------------------------------------------------------------------
// MFMA flash attention, R6: 4 waves/block, wave owns 32 q-rows (2 strips),
// block covers 128 q-rows. 64-key K/V tiles staged in LDS (shared by waves)
// with register prefetch issued after the post-store barrier (overlaps the
// whole compute phase). Row-sum of P via ones-B MFMA. Softmax in exp2 domain.
// R5 bug fixed: diagonal mask fires iff kt == ktw (a wave's 32 rows never
// cross a 64-block, so ktw is the diagonal tile for BOTH strips; the previous
// `kt*64+48 > qs` test missed qs%64==48 strips and admitted future keys).
// qh,kh: f16 [B*H][T][D] (q pre-scaled); vh: f16 [B*H][D][T]; yh: f16 [B*T][C].
// ---------------------------------------------------------------------------
__global__ __launch_bounds__(256, 3)
void attn_mfma_kernel(const ushort_t* __restrict__ qh, const ushort_t* __restrict__ kh,
                      const ushort_t* __restrict__ vh, ushort_t* __restrict__ yh)
{
    __shared__ ushort_t Ks[64 * 72];      // [key][d]
    __shared__ ushort_t Vs[64 * 72];      // [d][key] (V transposed)
    __shared__ ushort_t Ps[4][32 * 72];   // per-wave P strip [q][key]

    const int qi   = (int)gridDim.x - 1 - (int)blockIdx.x;  // big blocks first
    const int bh   = blockIdx.y;
    const int tid  = threadIdx.x;
    const int lane = tid & 63;
    const int w    = tid >> 6;
    const int lrow = lane & 15;
    const int quad = lane >> 4;
    const int q0w  = qi * 128 + w * 32;     // wave's first q row

    const ushort_t* qbase = qh + (size_t)bh * TT * DD;
    const ushort_t* kbase = kh + (size_t)bh * TT * DD;
    const ushort_t* vbase = vh + (size_t)bh * DD * TT;

    // Q A-fragments for both strips
    f16x8 aq[2][2];
    #pragma unroll
    for (int s = 0; s < 2; ++s) {
        aq[s][0] = *(const f16x8*)&qbase[(size_t)(q0w + s * 16 + lrow) * DD + quad * 8];
        aq[s][1] = *(const f16x8*)&qbase[(size_t)(q0w + s * 16 + lrow) * DD + 32 + quad * 8];
    }

    const f32x4 z = {0.f, 0.f, 0.f, 0.f};
    f32x4 o[2][4], ls[2];
    float mi[2][4];
    #pragma unroll
    for (int s = 0; s < 2; ++s) {
        ls[s] = z;
        #pragma unroll
        for (int i = 0; i < 4; ++i) { o[s][i] = z; mi[s][i] = -1e30f; }
    }
    f16x8 ones;
    #pragma unroll
    for (int i = 0; i < 8; ++i) ones[i] = (_Float16)1.0f;

    // staging: 256 threads x (2 K + 2 V) uint4; row ur/ur+32, 16B chunk uc
    const int ur = tid >> 3;            // 0..31
    const int uc = (tid & 7) * 8;       // halves

    const int ktmax = qi * 2 + 1;               // block's last key tile
    const int ktw   = (q0w + 31) >> 6;          // wave's last (= diagonal) tile

    // prefetch tile 0
    uint4 kr0 = *(const uint4*)&kbase[(size_t)ur * DD + uc];
    uint4 kr1 = *(const uint4*)&kbase[(size_t)(ur + 32) * DD + uc];
    uint4 vr0 = *(const uint4*)&vbase[(size_t)ur * TT + uc];
    uint4 vr1 = *(const uint4*)&vbase[(size_t)(ur + 32) * TT + uc];

    for (int kt = 0; kt <= ktmax; ++kt) {
        __syncthreads();                 // previous tile's readers done
        *(uint4*)&Ks[(ur)      * 72 + uc] = kr0;
        *(uint4*)&Ks[(ur + 32) * 72 + uc] = kr1;
        *(uint4*)&Vs[(ur)      * 72 + uc] = vr0;
        *(uint4*)&Vs[(ur + 32) * 72 + uc] = vr1;
        __syncthreads();                 // tile visible
        if (kt < ktmax) {                // prefetch next tile (overlaps compute)
            const int nb = (kt + 1) * 64;
            kr0 = *(const uint4*)&kbase[(size_t)(nb + ur) * DD + uc];
            kr1 = *(const uint4*)&kbase[(size_t)(nb + ur + 32) * DD + uc];
            vr0 = *(const uint4*)&vbase[(size_t)ur * TT + nb + uc];
            vr1 = *(const uint4*)&vbase[(size_t)(ur + 32) * TT + nb + uc];
        }
        if (kt > ktw) continue;          // inactive wave: barriers only

        // S = Q K^T for both strips (K-frags shared)
        f32x4 sv[2][4];
        #pragma unroll
        for (int c = 0; c < 4; ++c) {
            f16x8 b0 = *(const f16x8*)&Ks[(c * 16 + lrow) * 72 + quad * 8];
            f16x8 b1 = *(const f16x8*)&Ks[(c * 16 + lrow) * 72 + 32 + quad * 8];
            sv[0][c] = __builtin_amdgcn_mfma_f32_16x16x32_f16(aq[0][0], b0, z, 0, 0, 0);
            sv[0][c] = __builtin_amdgcn_mfma_f32_16x16x32_f16(aq[0][1], b1, sv[0][c], 0, 0, 0);
            sv[1][c] = __builtin_amdgcn_mfma_f32_16x16x32_f16(aq[1][0], b0, z, 0, 0, 0);
            sv[1][c] = __builtin_amdgcn_mfma_f32_16x16x32_f16(aq[1][1], b1, sv[1][c], 0, 0, 0);
        }

        // online softmax per strip (C-layout: row=quad*4+r, col=c*16+lrow)
        const bool dmask = (kt == ktw);  // diagonal tile for BOTH strips
        #pragma unroll
        for (int s = 0; s < 2; ++s) {
            const int qs = q0w + s * 16;
            #pragma unroll
            for (int r = 0; r < 4; ++r) {
                if (dmask) {
                    const int qg = qs + quad * 4 + r;
                    #pragma unroll
                    for (int c = 0; c < 4; ++c)
                        if (kt * 64 + c * 16 + lrow > qg) sv[s][c][r] = -3e38f;
                }
                float m = fmaxf(fmaxf(sv[s][0][r], sv[s][1][r]),
                                fmaxf(sv[s][2][r], sv[s][3][r]));
                #pragma unroll
                for (int off = 1; off < 16; off <<= 1)
                    m = fmaxf(m, __shfl_xor(m, off, 64));
                const float mnew  = fmaxf(mi[s][r], m);
                const float alpha = exp2f(mi[s][r] - mnew);
                mi[s][r] = mnew;
                #pragma unroll
                for (int c = 0; c < 4; ++c) {
                    const float p = exp2f(sv[s][c][r] - mnew);
                    Ps[w][(s * 16 + quad * 4 + r) * 72 + c * 16 + lrow] = f2h(p);
                }
                #pragma unroll
                for (int dt = 0; dt < 4; ++dt) o[s][dt][r] *= alpha;
                ls[s][r] *= alpha;
            }
        }

        // P back as A-frags (same-wave LDS RAW, in-order)
        f16x8 ap[2][2];
        #pragma unroll
        for (int s = 0; s < 2; ++s) {
            ap[s][0] = *(const f16x8*)&Ps[w][(s * 16 + lrow) * 72 + quad * 8];
            ap[s][1] = *(const f16x8*)&Ps[w][(s * 16 + lrow) * 72 + 32 + quad * 8];
        }
        // O += P V (V-frags shared across strips); row-sum via ones-B MFMA
        #pragma unroll
        for (int dt = 0; dt < 4; ++dt) {
            f16x8 b0 = *(const f16x8*)&Vs[(dt * 16 + lrow) * 72 + quad * 8];
            f16x8 b1 = *(const f16x8*)&Vs[(dt * 16 + lrow) * 72 + 32 + quad * 8];
            #pragma unroll
            for (int s = 0; s < 2; ++s) {
                o[s][dt] = __builtin_amdgcn_mfma_f32_16x16x32_f16(ap[s][0], b0, o[s][dt], 0, 0, 0);
                o[s][dt] = __builtin_amdgcn_mfma_f32_16x16x32_f16(ap[s][1], b1, o[s][dt], 0, 0, 0);
            }
        }
        #pragma unroll
        for (int s = 0; s < 2; ++s) {
            ls[s] = __builtin_amdgcn_mfma_f32_16x16x32_f16(ap[s][0], ones, ls[s], 0, 0, 0);
            ls[s] = __builtin_amdgcn_mfma_f32_16x16x32_f16(ap[s][1], ones, ls[s], 0, 0, 0);
        }
    }

    // normalize + write y f16 [B*T][C]
    const int b = bh >> 4, h = bh & 15;
    #pragma unroll
    for (int s = 0; s < 2; ++s)
        #pragma unroll
        for (int r = 0; r < 4; ++r) {
            const float inv = 1.0f / ls[s][r];
            const int t = q0w + s * 16 + quad * 4 + r;
            #pragma unroll
            for (int dt = 0; dt < 4; ++dt)
                yh[((size_t)b * TT + t) * CC + h * 64 + dt * 16 + lrow] =
                    f2h(o[s][dt][r] * inv);
        }
}

// ---------------------------------------------------------------------------
// ws layout (halves): qh | kh | vh (8.39M each) | xh 8.39M (yh aliases xh)
//                     | wat 3.15M | wpt 1.05M     ~ 75 MB
// ---------------------------------------------------------------------------
extern "C" void kernel_launch(void* const* d_in, const int* in_sizes, int n_in,
                              void* d_out, int out_size, void* d_ws, size_t ws_size,
                              hipStream_t stream) {
    const float* x      = (const float*)d_in[0];
    const float* w_attn = (const float*)d_in[1];
    const float* b_attn = (const float*)d_in[2];
    const float* w_proj = (const float*)d_in[3];
    const float* b_proj = (const float*)d_in[4];
    float* out = (float*)d_out;

    const size_t per = (size_t)BB * HH * TT * DD;      // 8,388,608
    ushort_t* qh  = (ushort_t*)d_ws;
    ushort_t* kh  = qh + per;
    ushort_t* vh  = kh + per;
    ushort_t* xh  = vh + per;
    ushort_t* yh  = xh;                                 // alias: xh dead after GEMM1
    ushort_t* wat = xh + (size_t)MM * CC;
    ushort_t* wpt = wat + (size_t)3 * CC * CC;

    cvt4_kernel<<<(MM * CC / 4 + 255) / 256, 256, 0, stream>>>(x, xh, MM * CC / 4);
    trcvt_kernel<<<dim3(3 * CC / 32, CC / 32), 256, 0, stream>>>(w_attn, wat, CC, 3 * CC);
    trcvt_kernel<<<dim3(CC / 32, CC / 32), 256, 0, stream>>>(w_proj, wpt, CC, CC);

    hgemm_kernel<3 * CC, true><<<dim3(3 * CC / 128, MM / 128), 256, 0, stream>>>(
        xh, wat, b_attn, nullptr, qh, kh, vh);

    // 4 waves/block, 128 q-rows/block: grid (16 q-blocks reversed, 64 heads)
    attn_mfma_kernel<<<dim3(TT / 128, BB * HH), 256, 0, stream>>>(qh, kh, vh, yh);

    hgemm_kernel<CC, false><<<dim3(CC / 128, MM / 128), 256, 0, stream>>>(
        yh, wpt, b_proj, out, nullptr, nullptr, nullptr);
}

// Round 8
// 282.209 us; speedup vs baseline: 1.4632x; 1.4190x over previous
//
#include <hip/hip_runtime.h>
#include <cmath>

#define BB 4
#define TT 2048
#define CC 1024
#define HH 16
#define DD 64
#define MM (BB*TT)   // 8192

typedef _Float16 f16x8 __attribute__((ext_vector_type(8)));
typedef _Float16 f16x4 __attribute__((ext_vector_type(4)));
typedef float f32x4 __attribute__((ext_vector_type(4)));
typedef unsigned short ushort_t;

// legacy K=16 f16 MFMA: spelled WITHOUT underscore before f16 (pre-gfx950
// naming; compiler fix-it verified R7)
#define MFMA16(a,b,c) __builtin_amdgcn_mfma_f32_16x16x16f16(a,b,c,0,0,0)

__device__ __forceinline__ unsigned short f2h(float f) {
    _Float16 h = (_Float16)f;
    return __builtin_bit_cast(unsigned short, h);
}

// async global->LDS, 16 bytes per lane (lane i -> base + i*16).
__device__ __forceinline__ void gld16(const void* gsrc, void* ldst) {
    void* g = const_cast<void*>(gsrc);
    __builtin_amdgcn_global_load_lds(
        (__attribute__((address_space(1))) void*)g,
        (__attribute__((address_space(3))) void*)ldst,
        16, 0, 0);
}

// ---------------------------------------------------------------------------
// prep: fp32 -> f16 (packed x4)
// ---------------------------------------------------------------------------
__global__ __launch_bounds__(256)
void cvt4_kernel(const float* __restrict__ in, ushort_t* __restrict__ out, long n4) {
    long i = (long)blockIdx.x * blockDim.x + threadIdx.x;
    if (i >= n4) return;
    float4 v = ((const float4*)in)[i];
    ushort4 o;
    o.x = f2h(v.x); o.y = f2h(v.y); o.z = f2h(v.z); o.w = f2h(v.w);
    ((ushort4*)out)[i] = o;
}

// ---------------------------------------------------------------------------
// prep: transpose + convert: in[K][N] fp32 -> out[N][K] f16. 32x32 tiles.
// ---------------------------------------------------------------------------
__global__ __launch_bounds__(256)
void trcvt_kernel(const float* __restrict__ in, ushort_t* __restrict__ out,
                  int K, int N) {
    __shared__ float T[32][33];
    const int tx = threadIdx.x & 31;
    const int ty = threadIdx.x >> 5;
    const int n0 = blockIdx.x * 32;
    const int k0 = blockIdx.y * 32;
    #pragma unroll
    for (int i = 0; i < 4; ++i)
        T[ty + i * 8][tx] = in[(size_t)(k0 + ty + i * 8) * N + n0 + tx];
    __syncthreads();
    #pragma unroll
    for (int i = 0; i < 4; ++i)
        out[(size_t)(n0 + ty + i * 8) * K + k0 + tx] = f2h(T[tx][ty + i * 8]);
}

// ---------------------------------------------------------------------------
// f16 MFMA GEMM (m97 structure): C[M,N] = A[M,1024] @ B[1024,N] + bias
// QKV epilogue: q,k f16 [B,H,T,D]; q pre-scaled by 8*log2(e) (exp2 softmax
// domain); v f16 TRANSPOSED [B,H,D,T].
// ---------------------------------------------------------------------------
template<int N, bool QKV>
__global__ __launch_bounds__(256)
void hgemm_kernel(const ushort_t* __restrict__ A, const ushort_t* __restrict__ Bt,
                  const float* __restrict__ bias, float* __restrict__ out,
                  ushort_t* __restrict__ qh, ushort_t* __restrict__ kh,
                  ushort_t* __restrict__ vh)
{
    const int K = 1024;
    __shared__ ushort_t As[128 * 32];
    __shared__ ushort_t Bs[128 * 32];

    const int tid  = threadIdx.x;
    const int lane = tid & 63;
    const int wave = tid >> 6;
    const int wm   = (wave & 1) * 64;
    const int wn   = (wave >> 1) * 64;
    const int m0   = blockIdx.y * 128;
    const int n0   = blockIdx.x * 128;
    const int lrow = lane & 15;
    const int quad = lane >> 4;

    const int u0 = wave * 64 + lane;
    const int u1 = u0 + 256;
    const size_t gA0 = (size_t)(m0 + (u0 >> 2)) * K + (u0 & 3) * 8;
    const size_t gA1 = (size_t)(m0 + (u1 >> 2)) * K + (u1 & 3) * 8;
    const size_t gB0 = (size_t)(n0 + (u0 >> 2)) * K + (u0 & 3) * 8;
    const size_t gB1 = (size_t)(n0 + (u1 >> 2)) * K + (u1 & 3) * 8;
    ushort_t* ldsA0 = &As[(wave * 64) * 8];
    ushort_t* ldsA1 = &As[(256 + wave * 64) * 8];
    ushort_t* ldsB0 = &Bs[(wave * 64) * 8];
    ushort_t* ldsB1 = &Bs[(256 + wave * 64) * 8];

    f32x4 acc[4][4];
    const f32x4 z = {0.f, 0.f, 0.f, 0.f};
    #pragma unroll
    for (int mt = 0; mt < 4; ++mt)
        #pragma unroll
        for (int nt = 0; nt < 4; ++nt)
            acc[mt][nt] = z;

    for (int kk = 0; kk < K; kk += 32) {
        gld16(&A[gA0 + kk],  ldsA0);
        gld16(&A[gA1 + kk],  ldsA1);
        gld16(&Bt[gB0 + kk], ldsB0);
        gld16(&Bt[gB1 + kk], ldsB1);
        __syncthreads();

        f16x8 af[4], bf[4];
        #pragma unroll
        for (int mt = 0; mt < 4; ++mt)
            af[mt] = *(const f16x8*)&As[(wm + mt * 16 + lrow) * 32 + quad * 8];
        #pragma unroll
        for (int nt = 0; nt < 4; ++nt)
            bf[nt] = *(const f16x8*)&Bs[(wn + nt * 16 + lrow) * 32 + quad * 8];
        #pragma unroll
        for (int mt = 0; mt < 4; ++mt)
            #pragma unroll
            for (int nt = 0; nt < 4; ++nt)
                acc[mt][nt] = __builtin_amdgcn_mfma_f32_16x16x32_f16(
                    af[mt], bf[nt], acc[mt][nt], 0, 0, 0);
        __syncthreads();
    }

    #pragma unroll
    for (int mt = 0; mt < 4; ++mt) {
        const int rbase = m0 + wm + mt * 16 + quad * 4;
        #pragma unroll
        for (int nt = 0; nt < 4; ++nt) {
            const int col = n0 + wn + nt * 16 + lrow;
            const float bv = bias[col];
            if (QKV) {
                const int which = col >> 10;
                const int c = col & 1023;
                const int h = c >> 6, d = c & 63;
                const int b = rbase >> 11, t0 = rbase & 2047;
                if (which == 2) {
                    ushort4 pk;
                    pk.x = f2h(acc[mt][nt][0] + bv);
                    pk.y = f2h(acc[mt][nt][1] + bv);
                    pk.z = f2h(acc[mt][nt][2] + bv);
                    pk.w = f2h(acc[mt][nt][3] + bv);
                    *(ushort4*)&vh[(((size_t)b * HH + h) * DD + d) * TT + t0] = pk;
                } else {
                    ushort_t* dst = which ? kh : qh;
                    // q carries score-scale 8 and log2(e) for exp2-domain softmax
                    const float sc = which ? 1.0f : 8.0f * 1.44269504088896f;
                    #pragma unroll
                    for (int r = 0; r < 4; ++r)
                        dst[(((size_t)b * HH + h) * TT + t0 + r) * DD + d] =
                            f2h((acc[mt][nt][r] + bv) * sc);
                }
            } else {
                #pragma unroll
                for (int r = 0; r < 4; ++r)
                    out[(size_t)(rbase + r) * N + col] = acc[mt][nt][r] + bv;
            }
        }
    }
}

// ---------------------------------------------------------------------------
// MFMA flash attention, R8 (= R7 + builtin spelling fix). Block = 4 waves;
// wave owns 16 q-rows; block covers a 64-row q-tile. Each block processes a
// BALANCED PAIR of q-tiles (qtA=31-p then qtB=p) -> every block runs exactly
// 33 k-tile iterations, grid 16x64 = 1024 equal blocks, 4/CU resident
// (LDS 18.4 KB, lb(256,4)).
// S^T = K*Q^T (operands swapped; same frag loads): each lane owns ONE q-row
// (q = q0w + lrow) -> softmax is in-lane + 2 shuffles, and P^T's C-layout IS
// the A-fragment of a 16x16x16 PV MFMA (lane holds P[q=lrow][key=quad*4+r]):
// no P LDS round-trip, no ones-MFMA. alpha/li cross to O's C-layout rows via
// shuffles. Register prefetch of next K/V tile after the post-store barrier.
// Softmax in exp2 domain (scale folded into q at GEMM1).
// qh,kh: f16 [B*H][T][D]; vh: f16 [B*H][D][T]; yh: f16 [B*T][C].
// ---------------------------------------------------------------------------
__global__ __launch_bounds__(256, 4)
void attn_mfma_kernel(const ushort_t* __restrict__ qh, const ushort_t* __restrict__ kh,
                      const ushort_t* __restrict__ vh, ushort_t* __restrict__ yh)
{
    __shared__ ushort_t Ks[64 * 72];      // [key][d]
    __shared__ ushort_t Vs[64 * 72];      // [d][key] (V transposed)

    const int pr   = blockIdx.x;          // pair index 0..15
    const int bh   = blockIdx.y;
    const int qtA  = 31 - pr;             // big tile first
    const int qtB  = pr;
    const int tid  = threadIdx.x;
    const int lane = tid & 63;
    const int w    = tid >> 6;
    const int lrow = lane & 15;
    const int quad = lane >> 4;

    const ushort_t* qbase = qh + (size_t)bh * TT * DD;
    const ushort_t* kbase = kh + (size_t)bh * TT * DD;
    const ushort_t* vbase = vh + (size_t)bh * DD * TT;
    const int b = bh >> 4, h = bh & 15;

    // staging: 256 threads x (2 K + 2 V) uint4; row ur/ur+32, 16B chunk uc
    const int ur = tid >> 3;            // 0..31
    const int uc = (tid & 7) * 8;       // halves

    int q0w = qtA * 64 + w * 16;
    f16x8 aq0 = *(const f16x8*)&qbase[(size_t)(q0w + lrow) * DD + quad * 8];
    f16x8 aq1 = *(const f16x8*)&qbase[(size_t)(q0w + lrow) * DD + 32 + quad * 8];

    const f32x4 z = {0.f, 0.f, 0.f, 0.f};
    f32x4 o[4] = {z, z, z, z};
    float mi = -1e30f, li = 0.f;

    // prefetch k-tile 0
    uint4 kr0 = *(const uint4*)&kbase[(size_t)ur * DD + uc];
    uint4 kr1 = *(const uint4*)&kbase[(size_t)(ur + 32) * DD + uc];
    uint4 vr0 = *(const uint4*)&vbase[(size_t)ur * TT + uc];
    uint4 vr1 = *(const uint4*)&vbase[(size_t)(ur + 32) * TT + uc];

    for (int i = 0; i <= 32; ++i) {
        if (i == qtA + 1) {
            // flush phase-A output; reset state for phase B
            #pragma unroll
            for (int r = 0; r < 4; ++r) {
                const float inv = 1.0f / __shfl(li, quad * 4 + r, 64);
                const int t = q0w + quad * 4 + r;
                #pragma unroll
                for (int dt = 0; dt < 4; ++dt)
                    yh[((size_t)b * TT + t) * CC + h * 64 + dt * 16 + lrow] =
                        f2h(o[dt][r] * inv);
            }
            q0w = qtB * 64 + w * 16;
            aq0 = *(const f16x8*)&qbase[(size_t)(q0w + lrow) * DD + quad * 8];
            aq1 = *(const f16x8*)&qbase[(size_t)(q0w + lrow) * DD + 32 + quad * 8];
            #pragma unroll
            for (int dt = 0; dt < 4; ++dt) o[dt] = z;
            mi = -1e30f; li = 0.f;
        }
        const int kt = (i <= qtA) ? i : i - qtA - 1;

        __syncthreads();                 // previous tile's readers done
        *(uint4*)&Ks[(ur)      * 72 + uc] = kr0;
        *(uint4*)&Ks[(ur + 32) * 72 + uc] = kr1;
        *(uint4*)&Vs[(ur)      * 72 + uc] = vr0;
        *(uint4*)&Vs[(ur + 32) * 72 + uc] = vr1;
        __syncthreads();                 // tile visible
        if (i < 32) {                    // prefetch next tile (overlaps compute)
            const int ni  = i + 1;
            const int nkt = (ni <= qtA) ? ni : ni - qtA - 1;
            const int nb  = nkt * 64;
            kr0 = *(const uint4*)&kbase[(size_t)(nb + ur) * DD + uc];
            kr1 = *(const uint4*)&kbase[(size_t)(nb + ur + 32) * DD + uc];
            vr0 = *(const uint4*)&vbase[(size_t)ur * TT + nb + uc];
            vr1 = *(const uint4*)&vbase[(size_t)(ur + 32) * TT + nb + uc];
        }

        // S^T = K Q^T : C[row=key=quad*4+r][col=q=lrow]
        f32x4 sv[4];
        #pragma unroll
        for (int c = 0; c < 4; ++c) {
            f16x8 ka = *(const f16x8*)&Ks[(c * 16 + lrow) * 72 + quad * 8];
            f16x8 kb = *(const f16x8*)&Ks[(c * 16 + lrow) * 72 + 32 + quad * 8];
            sv[c] = __builtin_amdgcn_mfma_f32_16x16x32_f16(ka, aq0, z, 0, 0, 0);
            sv[c] = __builtin_amdgcn_mfma_f32_16x16x32_f16(kb, aq1, sv[c], 0, 0, 0);
        }

        // softmax: each lane owns q-row qg; its 16 values are keys c*16+quad*4+r
        const int kt2 = kt * 64;
        const int qg  = q0w + lrow;
        const bool diag = (i == qtA) || (i == 32);
        if (diag) {
            #pragma unroll
            for (int c = 0; c < 4; ++c)
                #pragma unroll
                for (int r = 0; r < 4; ++r)
                    if (kt2 + c * 16 + quad * 4 + r > qg) sv[c][r] = -3e38f;
        }
        float m = -3e38f;
        #pragma unroll
        for (int c = 0; c < 4; ++c)
            #pragma unroll
            for (int r = 0; r < 4; ++r) m = fmaxf(m, sv[c][r]);
        m = fmaxf(m, __shfl_xor(m, 16, 64));
        m = fmaxf(m, __shfl_xor(m, 32, 64));
        const float mnew  = fmaxf(mi, m);
        const float alpha = exp2f(mi - mnew);
        mi = mnew;
        float rs = 0.f;
        f16x4 ap[4];
        #pragma unroll
        for (int c = 0; c < 4; ++c)
            #pragma unroll
            for (int r = 0; r < 4; ++r) {
                const float p = exp2f(sv[c][r] - mnew);
                rs += p;
                ap[c][r] = (_Float16)p;
            }
        rs += __shfl_xor(rs, 16, 64);
        rs += __shfl_xor(rs, 32, 64);
        li = li * alpha + rs;

        // broadcast alpha (held per q=lrow lane) to O's C-layout rows, scale O
        #pragma unroll
        for (int r = 0; r < 4; ++r) {
            const float ar = __shfl(alpha, quad * 4 + r, 64);
            #pragma unroll
            for (int dt = 0; dt < 4; ++dt) o[dt][r] *= ar;
        }

        // O += P V : P^T C-layout IS the 16x16x16 A-frag (lane: q=lrow,
        // key=quad*4+j). V B-frag from Vs[d][key]: b64 per (dt,c).
        #pragma unroll
        for (int dt = 0; dt < 4; ++dt)
            #pragma unroll
            for (int c = 0; c < 4; ++c) {
                f16x4 vb = *(const f16x4*)&Vs[(dt * 16 + lrow) * 72 + c * 16 + quad * 4];
                o[dt] = MFMA16(ap[c], vb, o[dt]);
            }
    }

    // final writeout (phase B)
    #pragma unroll
    for (int r = 0; r < 4; ++r) {
        const float inv = 1.0f / __shfl(li, quad * 4 + r, 64);
        const int t = q0w + quad * 4 + r;
        #pragma unroll
        for (int dt = 0; dt < 4; ++dt)
            yh[((size_t)b * TT + t) * CC + h * 64 + dt * 16 + lrow] =
                f2h(o[dt][r] * inv);
    }
}

// ---------------------------------------------------------------------------
// ws layout (halves): qh | kh | vh (8.39M each) | xh 8.39M (yh aliases xh)
//                     | wat 3.15M | wpt 1.05M     ~ 75 MB
// ---------------------------------------------------------------------------
extern "C" void kernel_launch(void* const* d_in, const int* in_sizes, int n_in,
                              void* d_out, int out_size, void* d_ws, size_t ws_size,
                              hipStream_t stream) {
    const float* x      = (const float*)d_in[0];
    const float* w_attn = (const float*)d_in[1];
    const float* b_attn = (const float*)d_in[2];
    const float* w_proj = (const float*)d_in[3];
    const float* b_proj = (const float*)d_in[4];
    float* out = (float*)d_out;

    const size_t per = (size_t)BB * HH * TT * DD;      // 8,388,608
    ushort_t* qh  = (ushort_t*)d_ws;
    ushort_t* kh  = qh + per;
    ushort_t* vh  = kh + per;
    ushort_t* xh  = vh + per;
    ushort_t* yh  = xh;                                 // alias: xh dead after GEMM1
    ushort_t* wat = xh + (size_t)MM * CC;
    ushort_t* wpt = wat + (size_t)3 * CC * CC;

    cvt4_kernel<<<(MM * CC / 4 + 255) / 256, 256, 0, stream>>>(x, xh, MM * CC / 4);
    trcvt_kernel<<<dim3(3 * CC / 32, CC / 32), 256, 0, stream>>>(w_attn, wat, CC, 3 * CC);
    trcvt_kernel<<<dim3(CC / 32, CC / 32), 256, 0, stream>>>(w_proj, wpt, CC, CC);

    hgemm_kernel<3 * CC, true><<<dim3(3 * CC / 128, MM / 128), 256, 0, stream>>>(
        xh, wat, b_attn, nullptr, qh, kh, vh);

    // 16 balanced q-tile pairs (x) x 64 heads (y); 4 waves per block
    attn_mfma_kernel<<<dim3(16, BB * HH), 256, 0, stream>>>(qh, kh, vh, yh);

    hgemm_kernel<CC, false><<<dim3(CC / 128, MM / 128), 256, 0, stream>>>(
        yh, wpt, b_proj, out, nullptr, nullptr, nullptr);
}